// Round 6
// baseline (605.985 us; speedup 1.0000x reference)
//
#include <hip/hip_runtime.h>
#include <hip/hip_cooperative_groups.h>

namespace cg = cooperative_groups;

// SpectralConv2d DHT spectral conv, B=16, Cin=Cout=64, H=W=128, modes 20x20.
// All stages linear; blurs folded into bases/weights.
//   fwd:  X(k1,k2) = sum_n1 [cos(th k1 n1) Pc - sin(th k1 n1) Ps
//                            - sin(th k1(n1+1)) Pc1 - cos(th k1(n1+1)) Ps1]
//        rotation folded:  X1 = D0 + D1 + ck*(D2c+D3s) + sk*(D3c-D2s)
//   inv (rank-42): y(u,v) = sum_{A=0..20} cosb(u,A)*RsC[A][v] + sinb(u,A)*RsS[A][v]
// SINGLE cooperative launch, 1024 blocks x 256 thr, LDS 23104 B ->
// 7 blocks/CU capacity vs 4 needed (big co-residency margin; r5's 40960B
// exact-fit was rejected by the runtime -> output stayed zero).
// Fallback: if cooperative launch errors, 4 regular launches w/ phase arg.
// Phases (grid.sync between):
//  A: blk0: L2g/RB2g; blk1: Tg; blk2: Lf2g; blk3-450: w1 blur+T -> wbT
//  B: per (b,c): xs stage -> GEMM (B via wave-uniform s_load, no Tg in LDS)
//     -> Pm2[20][256] scatter -> rotation-folded 6-dot combine -> X1
//  C: k3 m-major (400 blocks): blur once for 16 b, weights reused x4 b
//  D: k5b masked-v: waves 0-1 v0..31, waves 2-3 v96..127; v=32 pass; zero-fill

#define TWO_PI 6.283185307179586f
#define THETA (TWO_PI / 128.0f)

__device__ __forceinline__ void gauss9(float* g) {
  float s = 0.f;
#pragma unroll
  for (int t = 0; t < 9; ++t) { float d = (float)(t - 4); g[t] = expf(-0.5f * d * d); s += g[t]; }
  float inv = 1.f / s;
#pragma unroll
  for (int t = 0; t < 9; ++t) g[t] *= inv;
}

// phase: -1 = all phases w/ grid.sync (cooperative); 0..3 = single phase
__global__ void __launch_bounds__(256, 4) fused(
    const float* __restrict__ x, const float* __restrict__ w1,
    float* __restrict__ out, float* __restrict__ X1, float* __restrict__ O,
    float* __restrict__ wbT, float* __restrict__ Tg, float* __restrict__ Lf2g,
    float* __restrict__ L2g, float* __restrict__ RB2g, int phase) {
  __shared__ float lds[5776];   // 23104 B: max over phases (D: 400+5376)
  cg::grid_group grid = cg::this_grid();
  const bool all = (phase < 0);
  int tid = threadIdx.x;
  int blk = blockIdx.x;

  // ================= phase A: tables + w1 blur =================
  if (all || phase == 0) {
    if (blk == 1) {
      for (int i = tid; i < 5120; i += 256) {
        int n2 = i / 40, col = i - n2 * 40;
        int k2 = (col < 20) ? col : col - 20;
        float a = (float)((k2 * n2) & 127) * THETA;
        Tg[i] = (col < 20) ? cosf(a) : sinf(a);
      }
    } else if (blk == 2) {
      for (int i = tid; i < 10240; i += 256) {
        int k1 = i >> 9, t = i & 511;
        int q = t >> 7, n1 = t & 127;
        int nn = n1 + ((q >= 2) ? 1 : 0);
        float a = (float)((k1 * nn) & 127) * THETA;
        float v;
        if (q == 0) v = cosf(a);
        else if (q == 1) v = -sinf(a);
        else if (q == 2) v = -sinf(a);
        else v = -cosf(a);
        Lf2g[i] = v;
      }
    } else if (blk == 0) {
      // rank-42 bases. rows 0..20 = cos(th u A), 21..41 = sin(th u A)
      for (int i = tid; i < 5376; i += 256) {
        int u = i / 42, t = i - u * 42;
        int A = (t < 21) ? t : t - 21;
        float a = (float)((u * A) & 127) * THETA;
        lds[u * 44 + t] = (t < 21) ? cosf(a) : sinf(a);
      }
      __syncthreads();
      float g[9]; gauss9(g);
      for (int i = tid; i < 5376; i += 256) {
        int u = i / 42, t = i - u * 42;
        float acc = 0.f;
#pragma unroll
        for (int tp = 0; tp < 9; ++tp) {
          int uc = u - 4 + tp; uc = uc < 0 ? 0 : (uc > 127 ? 127 : uc);
          acc += g[tp] * lds[uc * 44 + t];
        }
        L2g[t * 128 + u] = acc;
        bool keep = (u <= 32) || (u >= 96);
        RB2g[t * 128 + u] = keep ? acc : 0.f;
      }
    } else if (blk < 451) {
      // blur w1 over Cout + transpose: wbT[(c*400+m)*64+o]
      int bb = blk - 3;
      int c = bb / 7, chunk = bb % 7;
      int m0 = chunk * 64;
      int mw = 400 - m0; if (mw > 64) mw = 64;
      for (int t = tid; t < 4096; t += 256) {
        int o = t >> 6, mm = t & 63;
        lds[o * 69 + mm] = (mm < mw) ? w1[(c * 64 + o) * 400 + m0 + mm] : 0.f;
      }
      __syncthreads();
      float g[9]; gauss9(g);
      for (int t = tid; t < 4096; t += 256) {
        int mm = t >> 6, o = t & 63;
        if (mm >= mw) continue;
        float acc = 0.f;
#pragma unroll
        for (int tp = 0; tp < 9; ++tp) {
          int oc = o - 4 + tp; oc = oc < 0 ? 0 : (oc > 63 ? 63 : oc);
          acc += g[tp] * lds[oc * 69 + mm];
        }
        wbT[(c * 400 + m0 + mm) * 64 + o] = acc;
      }
    }
  }
  if (all) grid.sync();

  // ================= phase B: fwd transform + combine, per (b,c) ==========
  // LDS: xs[32][132] (4224 fl) during GEMM; then Pm2[20][256] (5120 fl).
  // 4 waves; wave w owns cols 10w..10w+9 (B via wave-uniform s_load);
  // lane L owns rows 2L,2L+1 (1 ds_read_b64 per k).
  if (all || phase == 1) {
    int bc = blk;
    const float* xb = x + (long)bc * 16384;
    int w = __builtin_amdgcn_readfirstlane(tid >> 6);   // 0..3, uniform
    int L = tid & 63;
    const float* tgw = Tg + w * 10;                     // wave-uniform base
    float acc[2][10];
#pragma unroll
    for (int i = 0; i < 2; ++i)
#pragma unroll
      for (int j = 0; j < 10; ++j) acc[i][j] = 0.f;

    for (int ch = 0; ch < 4; ++ch) {
      __syncthreads();
      // stage: task = (n1-quad, n2l); 4 coalesced loads -> 1 b128 LDS write
      for (int t = tid; t < 1024; t += 256) {
        int n2l = t & 31, n1g = t >> 5;
        const float* gp = xb + n1g * 512 + ch * 32 + n2l;
        float4 v = make_float4(gp[0], gp[128], gp[256], gp[384]);
        *(float4*)&lds[n2l * 132 + n1g * 4] = v;
      }
      __syncthreads();
#pragma unroll 4
      for (int k = 0; k < 32; ++k) {
        float2 av = *(const float2*)&lds[k * 132 + 2 * L];   // rows 2L,2L+1
        const float* tr = tgw + (ch * 32 + k) * 40;          // uniform -> s_load
        float bv[10];
#pragma unroll
        for (int j = 0; j < 10; ++j) bv[j] = tr[j];
#pragma unroll
        for (int j = 0; j < 10; ++j) {
          acc[0][j] += av.x * bv[j];
          acc[1][j] += av.y * bv[j];
        }
      }
    }
    __syncthreads();
    // scatter into Pm2[20][256]: [0..128) Pc, [128..256) Ps; XOR swz (k2&7)<<2
#pragma unroll
    for (int j = 0; j < 10; ++j) {
      int col = w * 10 + j;
      int k2 = (col < 20) ? col : col - 20;
      int part = (col < 20) ? 0 : 128;
      int m = (k2 & 7) << 2;
      *(float2*)&lds[k2 * 256 + ((part + 2 * L) ^ m)] =
          make_float2(acc[0][j], acc[1][j]);
    }
    __syncthreads();
    // combine: 200 threads, 2 outputs (k2, k2+1) each; 6 separable dots
    if (tid < 200) {
      int k1 = tid / 10, k2 = (tid % 10) * 2;
      int m0 = (k2 & 7) << 2, m1 = ((k2 + 1) & 7) << 2;
      const float* lrow = Lf2g + k1 * 512;
      const float* p0 = lds + k2 * 256;
      const float* p1 = lds + (k2 + 1) * 256;
      float d0a = 0.f, d1a = 0.f, d2ca = 0.f, d2sa = 0.f, d3ca = 0.f, d3sa = 0.f;
      float d0b = 0.f, d1b = 0.f, d2cb = 0.f, d2sb = 0.f, d3cb = 0.f, d3sb = 0.f;
      for (int t = 0; t < 128; t += 4) {
        float4 l0 = *(const float4*)(lrow + t);
        float4 l1 = *(const float4*)(lrow + 128 + t);
        float4 l2 = *(const float4*)(lrow + 256 + t);
        float4 l3 = *(const float4*)(lrow + 384 + t);
        float4 pc0 = *(const float4*)(p0 + (t ^ m0));
        float4 ps0 = *(const float4*)(p0 + ((128 + t) ^ m0));
        float4 pc1 = *(const float4*)(p1 + (t ^ m1));
        float4 ps1 = *(const float4*)(p1 + ((128 + t) ^ m1));
        d0a += l0.x*pc0.x + l0.y*pc0.y + l0.z*pc0.z + l0.w*pc0.w;
        d1a += l1.x*ps0.x + l1.y*ps0.y + l1.z*ps0.z + l1.w*ps0.w;
        d2ca += l2.x*pc0.x + l2.y*pc0.y + l2.z*pc0.z + l2.w*pc0.w;
        d2sa += l2.x*ps0.x + l2.y*ps0.y + l2.z*ps0.z + l2.w*ps0.w;
        d3ca += l3.x*pc0.x + l3.y*pc0.y + l3.z*pc0.z + l3.w*pc0.w;
        d3sa += l3.x*ps0.x + l3.y*ps0.y + l3.z*ps0.z + l3.w*ps0.w;
        d0b += l0.x*pc1.x + l0.y*pc1.y + l0.z*pc1.z + l0.w*pc1.w;
        d1b += l1.x*ps1.x + l1.y*ps1.y + l1.z*ps1.z + l1.w*ps1.w;
        d2cb += l2.x*pc1.x + l2.y*pc1.y + l2.z*pc1.z + l2.w*pc1.w;
        d2sb += l2.x*ps1.x + l2.y*ps1.y + l2.z*ps1.z + l2.w*ps1.w;
        d3cb += l3.x*pc1.x + l3.y*pc1.y + l3.z*pc1.z + l3.w*pc1.w;
        d3sb += l3.x*ps1.x + l3.y*ps1.y + l3.z*ps1.z + l3.w*ps1.w;
      }
      float ska, cka, skb, ckb;
      sincosf(THETA * (float)k2, &ska, &cka);
      sincosf(THETA * (float)(k2 + 1), &skb, &ckb);
      X1[(k1 * 20 + k2) * 1024 + bc] = d0a + d1a + cka * (d2ca + d3sa) + ska * (d3ca - d2sa);
      X1[(k1 * 20 + k2 + 1) * 1024 + bc] = d0b + d1b + ckb * (d2cb + d3sb) + skb * (d3cb - d2sb);
    }
  }
  if (all) grid.sync();

  // ================= phase C: k3 m-major (400 blocks) =================
  if ((all || phase == 2) && blk < 400) {
    float (*Xp)[64] = (float(*)[64])lds;            // [16][64]
    float (*Xm)[64] = (float(*)[64])(lds + 1024);   // [16][64]
    int m = blk;
    int i = m / 20, j = m - i * 20;
    int nm = ((20 - i) % 20) * 20 + ((20 - j) % 20);
    const float sc = 0.5f / 16384.0f;
    float g[9]; gauss9(g);
    {
      int bl = tid >> 6, c = tid & 63;
#pragma unroll
      for (int it = 0; it < 4; ++it) {
        int b = bl * 4 + it;
        float sa = 0.f, sn = 0.f;
#pragma unroll
        for (int tp = 0; tp < 9; ++tp) {
          int bb = b - 4 + tp; bb = bb < 0 ? 0 : (bb > 15 ? 15 : bb);
          sa += g[tp] * X1[m * 1024 + bb * 64 + c];
          sn += g[tp] * X1[nm * 1024 + bb * 64 + c];
        }
        Xp[b][c] = (sa + sn) * sc; Xm[b][c] = (sa - sn) * sc;
      }
    }
    __syncthreads();
    int o = tid & 63, bq = tid >> 6;   // wave-uniform bq -> LDS broadcast reads
    float acc[4] = {0.f, 0.f, 0.f, 0.f};
#pragma unroll 4
    for (int c = 0; c < 64; ++c) {
      float wp = wbT[(c * 400 + m) * 64 + o];
      float wm = wbT[(c * 400 + nm) * 64 + o];
#pragma unroll
      for (int k = 0; k < 4; ++k)
        acc[k] += Xp[bq * 4 + k][c] * wp + Xm[bq * 4 + k][c] * wm;
    }
#pragma unroll
    for (int k = 0; k < 4; ++k)
      O[((bq * 4 + k) * 64 + o) * 400 + m] = acc[k];
  }
  if (all) grid.sync();

  // ================= phase D: k5b masked-v (per (b,o)) =================
  if (all || phase == 3) {
    float* Os = lds;             // [400]
    float* Rs = lds + 400;       // [42*128]
    int bo = blk;
    for (int t = tid; t < 400; t += 256) Os[t] = O[bo * 400 + t];
    __syncthreads();
    const float4* Bc4 = (const float4*)RB2g;             // rows 0..20
    const float4* Bs4 = (const float4*)(RB2g + 21 * 128);
    {
      int rg = tid & 7;                 // row-group (rg<7: rows 6rg..6rg+5)
      int vqIdx = tid >> 3;             // 0..31; live for vqIdx<17
      int vq = (vqIdx < 9) ? vqIdx : vqIdx + 15;   // 0..8, 24..31
      if (rg < 7 && vqIdx < 17) {
        int r0 = rg * 6;
        float4 a[6];
#pragma unroll
        for (int q = 0; q < 6; ++q) a[q] = make_float4(0.f, 0.f, 0.f, 0.f);
        for (int k2 = 0; k2 <= 20; ++k2) {
          float4 bc4 = Bc4[k2 * 32 + vq];
          float4 bs4 = Bs4[k2 * 32 + vq];
#pragma unroll
          for (int q = 0; q < 6; ++q) {
            int r = r0 + q;
            bool isS = (r >= 21);
            int A = isS ? (r - 21) : r;
            if (k2 < 20 && A < 20) {
              float ov = Os[A * 20 + k2];
              const float4 b = isS ? bs4 : bc4;
              float s = isS ? -ov : ov;
              a[q].x += s * b.x; a[q].y += s * b.y; a[q].z += s * b.z; a[q].w += s * b.w;
            }
            if (k2 >= 1 && A >= 1) {
              float ov = Os[(A - 1) * 20 + (k2 - 1)];
              const float4 b = isS ? bc4 : bs4;
              a[q].x -= ov * b.x; a[q].y -= ov * b.y; a[q].z -= ov * b.z; a[q].w -= ov * b.w;
            }
          }
        }
#pragma unroll
        for (int q = 0; q < 6; ++q)
          *(float4*)&Rs[(r0 + q) * 128 + vq * 4] = a[q];
      }
    }
    __syncthreads();
    long base = (long)bo * 16384;
    // main GEMM: half 0 (waves 0-1): v 0..31; half 1 (waves 2-3): v 96..127
    {
      int half = tid >> 7;
      int uu = (tid >> 3) & 15;  int u0 = uu * 8;
      int vv = tid & 7;          int v0 = half ? (96 + vv * 4) : vv * 4;
      float acc[8][4];
#pragma unroll
      for (int a = 0; a < 8; ++a)
#pragma unroll
        for (int b = 0; b < 4; ++b) acc[a][b] = 0.f;
      for (int r = 0; r < 42; ++r) {
        float4 a0 = *(const float4*)(L2g + r * 128 + u0);
        float4 a1 = *(const float4*)(L2g + r * 128 + u0 + 4);
        float4 b0 = *(const float4*)&Rs[r * 128 + v0];
        float av[8] = {a0.x, a0.y, a0.z, a0.w, a1.x, a1.y, a1.z, a1.w};
        float bv[4] = {b0.x, b0.y, b0.z, b0.w};
#pragma unroll
        for (int a = 0; a < 8; ++a)
#pragma unroll
          for (int b = 0; b < 4; ++b) acc[a][b] += av[a] * bv[b];
      }
#pragma unroll
      for (int a = 0; a < 8; ++a)
        *(float4*)&out[base + (u0 + a) * 128 + v0] =
            make_float4(acc[a][0], acc[a][1], acc[a][2], acc[a][3]);
    }
    // v = 32 column (only nonzero col in vq group 8)
    if (tid < 128) {
      float d = 0.f;
      for (int r = 0; r < 42; ++r) d += L2g[r * 128 + tid] * Rs[r * 128 + 32];
      out[base + tid * 128 + 32] = d;
    }
    // zero-fill v 33..95: per u, scalars 33-35 + float4 at 36..92
    float4 z4 = make_float4(0.f, 0.f, 0.f, 0.f);
    for (int jj = tid; jj < 2048; jj += 256) {
      int u = jj >> 4, s = jj & 15;
      long p = base + (long)u * 128;
      if (s == 15) { out[p + 33] = 0.f; out[p + 34] = 0.f; out[p + 35] = 0.f; }
      else *(float4*)&out[p + 36 + 4 * s] = z4;
    }
  }
}

extern "C" void kernel_launch(void* const* d_in, const int* in_sizes, int n_in,
                              void* d_out, int out_size, void* d_ws, size_t ws_size,
                              hipStream_t stream) {
  const float* x = (const float*)d_in[0];    // (16,64,128,128)
  const float* w1 = (const float*)d_in[1];   // (64,64,20,20)
  float* out = (float*)d_out;                // (16,64,128,128)
  float* ws = (float*)d_ws;

  float* X1 = ws;                  // 409,600
  float* O = X1 + 409600;          // 409,600
  float* wbT = O + 409600;         // 1,638,400
  float* Tg = wbT + 1638400;       // 5,120
  float* Lf2g = Tg + 5120;         // 10,240
  float* L2g = Lf2g + 10240;       // 5,376
  float* RB2g = L2g + 5376;        // 5,376   (total ~10 MB)

  int phase = -1;
  void* args[] = {(void*)&x, (void*)&w1, (void*)&out, (void*)&X1, (void*)&O,
                  (void*)&wbT, (void*)&Tg, (void*)&Lf2g, (void*)&L2g,
                  (void*)&RB2g, (void*)&phase};
  hipError_t err = hipLaunchCooperativeKernel((const void*)fused, dim3(1024),
                                              dim3(256), args, 0, stream);
  if (err != hipSuccess) {
    // fallback: 4 regular launches of the same kernel, one phase each
    for (int p = 0; p < 4; ++p)
      hipLaunchKernelGGL(fused, dim3(1024), dim3(256), 0, stream,
                         x, w1, out, X1, O, wbT, Tg, Lf2g, L2g, RB2g, p);
  }
}

// Round 7
// 192.450 us; speedup vs baseline: 3.1488x; 3.1488x over previous
//
#include <hip/hip_runtime.h>

// SpectralConv2d DHT spectral conv, B=16, Cin=Cout=64, H=W=128, modes 20x20.
// All stages linear; blurs folded into bases/weights.
//   fwd:  X(k1,k2) = sum_n1 [cos(th k1 n1) Pc - sin(th k1 n1) Ps
//                            - sin(th k1(n1+1)) Pc1 - cos(th k1(n1+1)) Ps1]
//   rotation folded ALL the way (verified algebra):
//       X1 = (Ac-Bs)*(1-sin(th(k1+k2))) - (As+Bc)*cos(th(k1+k2))
//       Ac=sum c*Pc, As=sum s*Pc, Bc=sum c*Ps, Bs=sum s*Ps; c,s = cos/sin(th k1 n1)
//   inv (rank-42): y(u,v) = sum_{A=0..20} cosb(u,A)*RsC[A][v] + sinb(u,A)*RsS[A][v]
// 3 launches (cooperative grid.sync REJECTED: r6 showed it forces cross-XCD
// L2 writeback per sync -> 519us, 99MB writes):
//  kBig (1473 blocks): blk0-447 w1 blur+T -> wbT; blk448 L2g/RB2g bases;
//       blk449+ self-contained k12 (Tg computed in-kernel, no Lf2g needed).
//  k3:  m-major (400 blocks): blur once for 16 b, weights reused x4 b.
//  k5b: masked-v: waves 0-1 v0..31, waves 2-3 v96..127; v=32 pass; zero-fill.

#define TWO_PI 6.283185307179586f
#define THETA (TWO_PI / 128.0f)

__device__ __forceinline__ void gauss9(float* g) {
  float s = 0.f;
#pragma unroll
  for (int t = 0; t < 9; ++t) { float d = (float)(t - 4); g[t] = expf(-0.5f * d * d); s += g[t]; }
  float inv = 1.f / s;
#pragma unroll
  for (int t = 0; t < 9; ++t) g[t] *= inv;
}

// ---- kBig: blk<448: w1 blur; blk==448: inverse bases; blk>=449: k12 (bc=blk-449)
// k12 LDS (40960 B, 4 blocks/CU):
//   phase 1: [0..5120) Tgs[128][40] (computed in-kernel); [5120..9344) xs[32][132]
//   phase 2: [0..5120) TgT[40][128] row-XOR ((r&7)<<2);
//            [5120..10240) Pm2[20][256] XOR ((k2&7)<<2): [0..128) Pc, [128..256) Ps
__global__ void __launch_bounds__(256, 4) kBig(
    const float* __restrict__ x, const float* __restrict__ w1,
    float* __restrict__ X1, float* __restrict__ wbT,
    float* __restrict__ L2g, float* __restrict__ RB2g) {
  __shared__ float lds[10240];
  int tid = threadIdx.x;
  int blk = blockIdx.x;

  if (blk < 448) {
    // blur w1 over Cout + transpose: wbT[(c*400+m)*64+o]
    int c = blk / 7, chunk = blk % 7;
    int m0 = chunk * 64;
    int mw = 400 - m0; if (mw > 64) mw = 64;
    for (int t = tid; t < 4096; t += 256) {
      int o = t >> 6, mm = t & 63;
      lds[o * 69 + mm] = (mm < mw) ? w1[(c * 64 + o) * 400 + m0 + mm] : 0.f;
    }
    __syncthreads();
    float g[9]; gauss9(g);
    for (int t = tid; t < 4096; t += 256) {
      int mm = t >> 6, o = t & 63;
      if (mm >= mw) continue;
      float acc = 0.f;
#pragma unroll
      for (int tp = 0; tp < 9; ++tp) {
        int oc = o - 4 + tp; oc = oc < 0 ? 0 : (oc > 63 ? 63 : oc);
        acc += g[tp] * lds[oc * 69 + mm];
      }
      wbT[(c * 400 + m0 + mm) * 64 + o] = acc;
    }
    return;
  }
  if (blk == 448) {
    // rank-42 inverse bases. rows 0..20 = cos(th u A), 21..41 = sin(th u A)
    for (int i = tid; i < 5376; i += 256) {
      int u = i / 42, t = i - u * 42;
      int A = (t < 21) ? t : t - 21;
      float a = (float)((u * A) & 127) * THETA;
      lds[u * 44 + t] = (t < 21) ? cosf(a) : sinf(a);
    }
    __syncthreads();
    float g[9]; gauss9(g);
    for (int i = tid; i < 5376; i += 256) {
      int u = i / 42, t = i - u * 42;
      float acc = 0.f;
#pragma unroll
      for (int tp = 0; tp < 9; ++tp) {
        int uc = u - 4 + tp; uc = uc < 0 ? 0 : (uc > 127 ? 127 : uc);
        acc += g[tp] * lds[uc * 44 + t];
      }
      L2g[t * 128 + u] = acc;
      bool keep = (u <= 32) || (u >= 96);
      RB2g[t * 128 + u] = keep ? acc : 0.f;
    }
    return;
  }

  // ---------------- k12: one block per (b,c) ----------------
  int bc = blk - 449;
  const float* xb = x + (long)bc * 16384;

  // Tgs[n2][col]: col<20 cos(th k2 n2), col>=20 sin. 10 sincos/thread.
  for (int i = tid; i < 2560; i += 256) {
    int n2 = i / 20, k2 = i - n2 * 20;
    float s, c;
    sincosf((float)((k2 * n2) & 127) * THETA, &s, &c);
    lds[n2 * 40 + k2] = c;
    lds[n2 * 40 + 20 + k2] = s;
  }

  int rg = tid & 31, cg = tid >> 5;   // 32 row-groups x 8 col-groups
  int r0 = rg * 4, c0 = cg * 5;
  float acc[4][5];
#pragma unroll
  for (int i = 0; i < 4; ++i)
#pragma unroll
    for (int j = 0; j < 5; ++j) acc[i][j] = 0.f;

  float* xs = lds + 5120;             // [32][132]
  for (int ch = 0; ch < 4; ++ch) {
    __syncthreads();
    // stage: task = (n1-quad, n2l); 4 coalesced loads -> 1 b128 LDS write
    for (int t = tid; t < 1024; t += 256) {
      int n2l = t & 31, n1g = t >> 5;
      const float* gp = xb + n1g * 512 + ch * 32 + n2l;
      float4 v = make_float4(gp[0], gp[128], gp[256], gp[384]);
      *(float4*)&xs[n2l * 132 + n1g * 4] = v;
    }
    __syncthreads();
#pragma unroll 4
    for (int k = 0; k < 32; ++k) {
      float4 av = *(const float4*)&xs[k * 132 + r0];      // conflict-free b128
      const float* tr = lds + (ch * 32 + k) * 40 + c0;    // 2-addr broadcast
      float avv[4] = {av.x, av.y, av.z, av.w};
      float bvv[5] = {tr[0], tr[1], tr[2], tr[3], tr[4]};
#pragma unroll
      for (int i = 0; i < 4; ++i)
#pragma unroll
        for (int j = 0; j < 5; ++j) acc[i][j] += avv[i] * bvv[j];
    }
  }
  __syncthreads();
  // TgT build (overwrites Tgs): row r<20: cos(th r t); r>=20: sin(th (r-20) t)
  // stored at r*128 + (t ^ ((r&7)<<2)) -> conflict-free strided col reads
  for (int i = tid; i < 2560; i += 256) {
    int k1 = i >> 7, t = i & 127;
    float s, c;
    sincosf((float)((k1 * t) & 127) * THETA, &s, &c);
    lds[k1 * 128 + (t ^ ((k1 & 7) << 2))] = c;
    lds[(20 + k1) * 128 + (t ^ (((20 + k1) & 7) << 2))] = s;
  }
  // scatter acc into Pm2 (region2; overwrites xs — all GEMM reads done)
#pragma unroll
  for (int j = 0; j < 5; ++j) {
    int col = c0 + j;
    int k2 = (col < 20) ? col : col - 20;
    int part = (col < 20) ? 0 : 128;
    int m = (k2 & 7) << 2;
    *(float4*)&lds[5120 + k2 * 256 + ((part + r0) ^ m)] =
        make_float4(acc[0][j], acc[1][j], acc[2][j], acc[3][j]);
  }
  __syncthreads();
  // combine: 200 threads, 2 outputs (k2, k2+1); 4 dots each vs TgT rows
  if (tid < 200) {
    int k1 = tid / 10, k2 = (tid % 10) * 2;
    int mc = (k1 & 7) << 2, ms = ((20 + k1) & 7) << 2;
    int m0 = (k2 & 7) << 2, m1 = ((k2 + 1) & 7) << 2;
    const float* tgc = lds + k1 * 128;
    const float* tgs = lds + (20 + k1) * 128;
    const float* p0 = lds + 5120 + k2 * 256;
    const float* p1 = lds + 5120 + (k2 + 1) * 256;
    float Ac0 = 0.f, As0 = 0.f, Bc0 = 0.f, Bs0 = 0.f;
    float Ac1 = 0.f, As1 = 0.f, Bc1 = 0.f, Bs1 = 0.f;
    for (int t = 0; t < 128; t += 4) {
      float4 tc = *(const float4*)(tgc + (t ^ mc));
      float4 ts = *(const float4*)(tgs + (t ^ ms));
      float4 pc0 = *(const float4*)(p0 + (t ^ m0));
      float4 ps0 = *(const float4*)(p0 + 128 + (t ^ m0));
      float4 pc1 = *(const float4*)(p1 + (t ^ m1));
      float4 ps1 = *(const float4*)(p1 + 128 + (t ^ m1));
      Ac0 += tc.x*pc0.x + tc.y*pc0.y + tc.z*pc0.z + tc.w*pc0.w;
      As0 += ts.x*pc0.x + ts.y*pc0.y + ts.z*pc0.z + ts.w*pc0.w;
      Bc0 += tc.x*ps0.x + tc.y*ps0.y + tc.z*ps0.z + tc.w*ps0.w;
      Bs0 += ts.x*ps0.x + ts.y*ps0.y + ts.z*ps0.z + ts.w*ps0.w;
      Ac1 += tc.x*pc1.x + tc.y*pc1.y + tc.z*pc1.z + tc.w*pc1.w;
      As1 += ts.x*pc1.x + ts.y*pc1.y + ts.z*pc1.z + ts.w*pc1.w;
      Bc1 += tc.x*ps1.x + tc.y*ps1.y + tc.z*ps1.z + tc.w*ps1.w;
      Bs1 += ts.x*ps1.x + ts.y*ps1.y + ts.z*ps1.z + ts.w*ps1.w;
    }
    float sa, ca, sb, cb;
    sincosf(THETA * (float)(k1 + k2), &sa, &ca);
    sincosf(THETA * (float)(k1 + k2 + 1), &sb, &cb);
    X1[(k1 * 20 + k2) * 1024 + bc] = (Ac0 - Bs0) * (1.f - sa) - (As0 + Bc0) * ca;
    X1[(k1 * 20 + k2 + 1) * 1024 + bc] = (Ac1 - Bs1) * (1.f - sb) - (As1 + Bc1) * cb;
  }
}

// ---- k3: m-major. One block per m (400 blocks). O[(b*64+o)*400+m]
__global__ void k3_mix(const float* __restrict__ X1, const float* __restrict__ wbT,
                       float* __restrict__ O) {
  __shared__ float Xp[16][64], Xm[16][64];
  int m = blockIdx.x;
  int i = m / 20, j = m - i * 20;
  int nm = ((20 - i) % 20) * 20 + ((20 - j) % 20);
  int tid = threadIdx.x;
  const float sc = 0.5f / 16384.0f;
  float g[9]; gauss9(g);
  {
    int bl = tid >> 6, c = tid & 63;
#pragma unroll
    for (int it = 0; it < 4; ++it) {
      int b = bl * 4 + it;
      float sa = 0.f, sn = 0.f;
#pragma unroll
      for (int tp = 0; tp < 9; ++tp) {
        int bb = b - 4 + tp; bb = bb < 0 ? 0 : (bb > 15 ? 15 : bb);
        sa += g[tp] * X1[m * 1024 + bb * 64 + c];
        sn += g[tp] * X1[nm * 1024 + bb * 64 + c];
      }
      Xp[b][c] = (sa + sn) * sc; Xm[b][c] = (sa - sn) * sc;
    }
  }
  __syncthreads();
  int o = tid & 63, bq = tid >> 6;   // wave-uniform bq -> LDS broadcast reads
  float acc[4] = {0.f, 0.f, 0.f, 0.f};
#pragma unroll 4
  for (int c = 0; c < 64; ++c) {
    float wp = wbT[(c * 400 + m) * 64 + o];
    float wm = wbT[(c * 400 + nm) * 64 + o];
#pragma unroll
    for (int k = 0; k < 4; ++k)
      acc[k] += Xp[bq * 4 + k][c] * wp + Xm[bq * 4 + k][c] * wm;
  }
#pragma unroll
  for (int k = 0; k < 4; ++k)
    O[((bq * 4 + k) * 64 + o) * 400 + m] = acc[k];
}

// ---- k5b: per (b,o). Only v in [0,32] u [96,127] nonzero (RB2g mask).
__global__ void __launch_bounds__(256) k5b_final(const float* __restrict__ O,
                                                 const float* __restrict__ L2g,
                                                 const float* __restrict__ RB2g,
                                                 float* __restrict__ out) {
  __shared__ float Os[400];
  __shared__ float Rs[42 * 128];
  int bo = blockIdx.x, tid = threadIdx.x;
  for (int t = tid; t < 400; t += 256) Os[t] = O[bo * 400 + t];
  __syncthreads();
  const float4* Bc4 = (const float4*)RB2g;             // rows 0..20
  const float4* Bs4 = (const float4*)(RB2g + 21 * 128);
  {
    int rg = tid & 7;                 // row-group (rg<7: rows 6rg..6rg+5)
    int vqIdx = tid >> 3;             // 0..31; live for vqIdx<17
    int vq = (vqIdx < 9) ? vqIdx : vqIdx + 15;   // 0..8, 24..31
    if (rg < 7 && vqIdx < 17) {
      int r0 = rg * 6;
      float4 a[6];
#pragma unroll
      for (int q = 0; q < 6; ++q) a[q] = make_float4(0.f, 0.f, 0.f, 0.f);
      for (int k2 = 0; k2 <= 20; ++k2) {
        float4 bc4 = Bc4[k2 * 32 + vq];
        float4 bs4 = Bs4[k2 * 32 + vq];
#pragma unroll
        for (int q = 0; q < 6; ++q) {
          int r = r0 + q;
          bool isS = (r >= 21);
          int A = isS ? (r - 21) : r;
          if (k2 < 20 && A < 20) {
            float ov = Os[A * 20 + k2];
            const float4 b = isS ? bs4 : bc4;
            float s = isS ? -ov : ov;
            a[q].x += s * b.x; a[q].y += s * b.y; a[q].z += s * b.z; a[q].w += s * b.w;
          }
          if (k2 >= 1 && A >= 1) {
            float ov = Os[(A - 1) * 20 + (k2 - 1)];
            const float4 b = isS ? bc4 : bs4;
            a[q].x -= ov * b.x; a[q].y -= ov * b.y; a[q].z -= ov * b.z; a[q].w -= ov * b.w;
          }
        }
      }
#pragma unroll
      for (int q = 0; q < 6; ++q)
        *(float4*)&Rs[(r0 + q) * 128 + vq * 4] = a[q];
    }
  }
  __syncthreads();
  long base = (long)bo * 16384;
  // main GEMM: half 0 (waves 0-1): v 0..31; half 1 (waves 2-3): v 96..127
  {
    int half = tid >> 7;
    int uu = (tid >> 3) & 15;  int u0 = uu * 8;
    int vv = tid & 7;          int v0 = half ? (96 + vv * 4) : vv * 4;
    float acc[8][4];
#pragma unroll
    for (int a = 0; a < 8; ++a)
#pragma unroll
      for (int b = 0; b < 4; ++b) acc[a][b] = 0.f;
    for (int r = 0; r < 42; ++r) {
      float4 a0 = *(const float4*)(L2g + r * 128 + u0);
      float4 a1 = *(const float4*)(L2g + r * 128 + u0 + 4);
      float4 b0 = *(const float4*)&Rs[r * 128 + v0];
      float av[8] = {a0.x, a0.y, a0.z, a0.w, a1.x, a1.y, a1.z, a1.w};
      float bv[4] = {b0.x, b0.y, b0.z, b0.w};
#pragma unroll
      for (int a = 0; a < 8; ++a)
#pragma unroll
        for (int b = 0; b < 4; ++b) acc[a][b] += av[a] * bv[b];
    }
#pragma unroll
    for (int a = 0; a < 8; ++a)
      *(float4*)&out[base + (u0 + a) * 128 + v0] =
          make_float4(acc[a][0], acc[a][1], acc[a][2], acc[a][3]);
  }
  // v = 32 column (only nonzero col in vq group 8)
  if (tid < 128) {
    float d = 0.f;
    for (int r = 0; r < 42; ++r) d += L2g[r * 128 + tid] * Rs[r * 128 + 32];
    out[base + tid * 128 + 32] = d;
  }
  // zero-fill v 33..95: per u, scalars 33-35 + float4 at 36..92
  float4 z4 = make_float4(0.f, 0.f, 0.f, 0.f);
  for (int jj = tid; jj < 2048; jj += 256) {
    int u = jj >> 4, s = jj & 15;
    long p = base + (long)u * 128;
    if (s == 15) { out[p + 33] = 0.f; out[p + 34] = 0.f; out[p + 35] = 0.f; }
    else *(float4*)&out[p + 36 + 4 * s] = z4;
  }
}

extern "C" void kernel_launch(void* const* d_in, const int* in_sizes, int n_in,
                              void* d_out, int out_size, void* d_ws, size_t ws_size,
                              hipStream_t stream) {
  const float* x = (const float*)d_in[0];    // (16,64,128,128)
  const float* w1 = (const float*)d_in[1];   // (64,64,20,20)
  float* out = (float*)d_out;                // (16,64,128,128)
  float* ws = (float*)d_ws;

  float* X1 = ws;                  // 409,600
  float* O = X1 + 409600;          // 409,600
  float* wbT = O + 409600;         // 1,638,400
  float* L2g = wbT + 1638400;      // 5,376
  float* RB2g = L2g + 5376;        // 5,376   (total ~10 MB)

  hipLaunchKernelGGL(kBig, dim3(1473), dim3(256), 0, stream,
                     x, w1, X1, wbT, L2g, RB2g);
  hipLaunchKernelGGL(k3_mix, dim3(400), dim3(256), 0, stream, X1, wbT, O);
  hipLaunchKernelGGL(k5b_final, dim3(1024), dim3(256), 0, stream, O, L2g, RB2g, out);
}

// Round 8
// 187.862 us; speedup vs baseline: 3.2257x; 1.0244x over previous
//
#include <hip/hip_runtime.h>

// SpectralConv2d DHT spectral conv, B=16, Cin=Cout=64, H=W=128, modes 20x20.
// All stages linear; blurs folded into bases/weights.
//   fwd:  X(k1,k2) = sum_n1 [cos(th k1 n1) Pc - sin(th k1 n1) Ps
//                            - sin(th k1(n1+1)) Pc1 - cos(th k1(n1+1)) Ps1]
//   rotation folded ALL the way (verified algebra):
//       X1 = (Ac-Bs)*(1-sin(th(k1+k2))) - (As+Bc)*cos(th(k1+k2))
//       Ac=sum c*Pc, As=sum s*Pc, Bc=sum c*Ps, Bs=sum s*Ps; c,s = cos/sin(th k1 n1)
//   inv (rank-42): y(u,v) = sum_{A=0..20} cosb(u,A)*RsC[A][v] + sinb(u,A)*RsS[A][v]
// 3 launches (cooperative grid.sync REJECTED: r6 = 519us, cross-XCD writeback):
//  kBig (961 blocks): blk0-447 w1 blur+T; blk448 L2g/RB2g; blk449+ k12 handling
//       TWO images (bc=2i,2i+1) per block: B-reads (5 ds_read_b32 broadcast)
//       amortized over 2 A-frags -> LDS-pipe cost per image ~35% lower (r7 was
//       LDS-bound: 1xb128+5xb32 per wave-k = ~35us of 58).
//       Staging chunk = 16 n2 (8 chunks) so dual xs fits r7's footprint.
//  k3:  m-major (400 blocks): blur once for 16 b, weights reused x4 b.
//  k5b: masked-v: waves 0-1 v0..31, waves 2-3 v96..127; v=32 pass; zero-fill.

#define TWO_PI 6.283185307179586f
#define THETA (TWO_PI / 128.0f)

__device__ __forceinline__ void gauss9(float* g) {
  float s = 0.f;
#pragma unroll
  for (int t = 0; t < 9; ++t) { float d = (float)(t - 4); g[t] = expf(-0.5f * d * d); s += g[t]; }
  float inv = 1.f / s;
#pragma unroll
  for (int t = 0; t < 9; ++t) g[t] *= inv;
}

// ---- kBig: blk<448: w1 blur; blk==448: inverse bases; blk>=449: k12 (2 images)
// k12 LDS (40960 B):
//   phase 1: [0..5120) Tgs[128][40]; [5120..7232) xs0[16][132]; [7232..9344) xs1
//   phase 2: [0..5120) TgT[40][128] row-XOR ((r&7)<<2);
//            [5120..10240) Pm2[20][256] XOR ((k2&7)<<2) — scatter+combine per img
__global__ void __launch_bounds__(256, 4) kBig(
    const float* __restrict__ x, const float* __restrict__ w1,
    float* __restrict__ X1, float* __restrict__ wbT,
    float* __restrict__ L2g, float* __restrict__ RB2g) {
  __shared__ float lds[10240];
  int tid = threadIdx.x;
  int blk = blockIdx.x;

  if (blk < 448) {
    // blur w1 over Cout + transpose: wbT[(c*400+m)*64+o]
    int c = blk / 7, chunk = blk % 7;
    int m0 = chunk * 64;
    int mw = 400 - m0; if (mw > 64) mw = 64;
    for (int t = tid; t < 4096; t += 256) {
      int o = t >> 6, mm = t & 63;
      lds[o * 69 + mm] = (mm < mw) ? w1[(c * 64 + o) * 400 + m0 + mm] : 0.f;
    }
    __syncthreads();
    float g[9]; gauss9(g);
    for (int t = tid; t < 4096; t += 256) {
      int mm = t >> 6, o = t & 63;
      if (mm >= mw) continue;
      float acc = 0.f;
#pragma unroll
      for (int tp = 0; tp < 9; ++tp) {
        int oc = o - 4 + tp; oc = oc < 0 ? 0 : (oc > 63 ? 63 : oc);
        acc += g[tp] * lds[oc * 69 + mm];
      }
      wbT[(c * 400 + m0 + mm) * 64 + o] = acc;
    }
    return;
  }
  if (blk == 448) {
    // rank-42 inverse bases. rows 0..20 = cos(th u A), 21..41 = sin(th u A)
    for (int i = tid; i < 5376; i += 256) {
      int u = i / 42, t = i - u * 42;
      int A = (t < 21) ? t : t - 21;
      float a = (float)((u * A) & 127) * THETA;
      lds[u * 44 + t] = (t < 21) ? cosf(a) : sinf(a);
    }
    __syncthreads();
    float g[9]; gauss9(g);
    for (int i = tid; i < 5376; i += 256) {
      int u = i / 42, t = i - u * 42;
      float acc = 0.f;
#pragma unroll
      for (int tp = 0; tp < 9; ++tp) {
        int uc = u - 4 + tp; uc = uc < 0 ? 0 : (uc > 127 ? 127 : uc);
        acc += g[tp] * lds[uc * 44 + t];
      }
      L2g[t * 128 + u] = acc;
      bool keep = (u <= 32) || (u >= 96);
      RB2g[t * 128 + u] = keep ? acc : 0.f;
    }
    return;
  }

  // ---------------- k12: one block per image PAIR ----------------
  int bc0 = (blk - 449) * 2;
  const float* xb0 = x + (long)bc0 * 16384;
  const float* xb1 = xb0 + 16384;

  // Tgs[n2][col]: col<20 cos(th k2 n2), col>=20 sin. 10 sincos/thread, once.
  for (int i = tid; i < 2560; i += 256) {
    int n2 = i / 20, k2 = i - n2 * 20;
    float s, c;
    sincosf((float)((k2 * n2) & 127) * THETA, &s, &c);
    lds[n2 * 40 + k2] = c;
    lds[n2 * 40 + 20 + k2] = s;
  }

  int rg = tid & 31, cg = tid >> 5;   // 32 row-groups x 8 col-groups
  int r0 = rg * 4, c0 = cg * 5;
  float acc0[4][5], acc1[4][5];
#pragma unroll
  for (int i = 0; i < 4; ++i)
#pragma unroll
    for (int j = 0; j < 5; ++j) { acc0[i][j] = 0.f; acc1[i][j] = 0.f; }

  float* xs0 = lds + 5120;            // [16][132]
  float* xs1 = lds + 7232;            // [16][132]
  for (int ch = 0; ch < 8; ++ch) {
    __syncthreads();
    // stage both images: task = (img, n2l, n1g); im uniform per iteration
#pragma unroll 4
    for (int it = 0; it < 4; ++it) {
      int t = tid + it * 256;
      int n2l = t & 15, n1g = (t >> 4) & 31, im = t >> 9;
      const float* gp = (im ? xb1 : xb0) + n1g * 512 + ch * 16 + n2l;
      float4 v = make_float4(gp[0], gp[128], gp[256], gp[384]);
      float* dst = im ? xs1 : xs0;
      *(float4*)&dst[n2l * 132 + n1g * 4] = v;
    }
    __syncthreads();
#pragma unroll 4
    for (int k = 0; k < 16; ++k) {
      float4 a0 = *(const float4*)&xs0[k * 132 + r0];     // conflict-free b128
      float4 a1 = *(const float4*)&xs1[k * 132 + r0];
      const float* tr = lds + (ch * 16 + k) * 40 + c0;    // broadcast b32 x5
      float bv[5] = {tr[0], tr[1], tr[2], tr[3], tr[4]};
      float a0v[4] = {a0.x, a0.y, a0.z, a0.w};
      float a1v[4] = {a1.x, a1.y, a1.z, a1.w};
#pragma unroll
      for (int i = 0; i < 4; ++i)
#pragma unroll
        for (int j = 0; j < 5; ++j) {
          acc0[i][j] += a0v[i] * bv[j];
          acc1[i][j] += a1v[i] * bv[j];
        }
    }
  }
  __syncthreads();
  // TgT build (overwrites Tgs): row r<20: cos(th r t); r>=20: sin(th (r-20) t)
  // stored at r*128 + (t ^ ((r&7)<<2)) -> conflict-free strided col reads
  for (int i = tid; i < 2560; i += 256) {
    int k1 = i >> 7, t = i & 127;
    float s, c;
    sincosf((float)((k1 * t) & 127) * THETA, &s, &c);
    lds[k1 * 128 + (t ^ ((k1 & 7) << 2))] = c;
    lds[(20 + k1) * 128 + (t ^ (((20 + k1) & 7) << 2))] = s;
  }
  // ---- image 0: scatter + combine ----
#pragma unroll
  for (int j = 0; j < 5; ++j) {
    int col = c0 + j;
    int k2 = (col < 20) ? col : col - 20;
    int part = (col < 20) ? 0 : 128;
    int m = (k2 & 7) << 2;
    *(float4*)&lds[5120 + k2 * 256 + ((part + r0) ^ m)] =
        make_float4(acc0[0][j], acc0[1][j], acc0[2][j], acc0[3][j]);
  }
  __syncthreads();
  if (tid < 200) {
    int k1 = tid / 10, k2 = (tid % 10) * 2;
    int mc = (k1 & 7) << 2, ms = ((20 + k1) & 7) << 2;
    int m0 = (k2 & 7) << 2, m1 = ((k2 + 1) & 7) << 2;
    const float* tgc = lds + k1 * 128;
    const float* tgs = lds + (20 + k1) * 128;
    const float* p0 = lds + 5120 + k2 * 256;
    const float* p1 = lds + 5120 + (k2 + 1) * 256;
    float Ac0 = 0.f, As0 = 0.f, Bc0 = 0.f, Bs0 = 0.f;
    float Ac1 = 0.f, As1 = 0.f, Bc1 = 0.f, Bs1 = 0.f;
    for (int t = 0; t < 128; t += 4) {
      float4 tc = *(const float4*)(tgc + (t ^ mc));
      float4 ts = *(const float4*)(tgs + (t ^ ms));
      float4 pc0 = *(const float4*)(p0 + (t ^ m0));
      float4 ps0 = *(const float4*)(p0 + 128 + (t ^ m0));
      float4 pc1 = *(const float4*)(p1 + (t ^ m1));
      float4 ps1 = *(const float4*)(p1 + 128 + (t ^ m1));
      Ac0 += tc.x*pc0.x + tc.y*pc0.y + tc.z*pc0.z + tc.w*pc0.w;
      As0 += ts.x*pc0.x + ts.y*pc0.y + ts.z*pc0.z + ts.w*pc0.w;
      Bc0 += tc.x*ps0.x + tc.y*ps0.y + tc.z*ps0.z + tc.w*ps0.w;
      Bs0 += ts.x*ps0.x + ts.y*ps0.y + ts.z*ps0.z + ts.w*ps0.w;
      Ac1 += tc.x*pc1.x + tc.y*pc1.y + tc.z*pc1.z + tc.w*pc1.w;
      As1 += ts.x*pc1.x + ts.y*pc1.y + ts.z*pc1.z + ts.w*pc1.w;
      Bc1 += tc.x*ps1.x + tc.y*ps1.y + tc.z*ps1.z + tc.w*ps1.w;
      Bs1 += ts.x*ps1.x + ts.y*ps1.y + ts.z*ps1.z + ts.w*ps1.w;
    }
    float sa, ca, sb, cb;
    sincosf(THETA * (float)(k1 + k2), &sa, &ca);
    sincosf(THETA * (float)(k1 + k2 + 1), &sb, &cb);
    X1[(k1 * 20 + k2) * 1024 + bc0] = (Ac0 - Bs0) * (1.f - sa) - (As0 + Bc0) * ca;
    X1[(k1 * 20 + k2 + 1) * 1024 + bc0] = (Ac1 - Bs1) * (1.f - sb) - (As1 + Bc1) * cb;
  }
  __syncthreads();   // combine img0 done reading Pm2
  // ---- image 1: scatter + combine ----
#pragma unroll
  for (int j = 0; j < 5; ++j) {
    int col = c0 + j;
    int k2 = (col < 20) ? col : col - 20;
    int part = (col < 20) ? 0 : 128;
    int m = (k2 & 7) << 2;
    *(float4*)&lds[5120 + k2 * 256 + ((part + r0) ^ m)] =
        make_float4(acc1[0][j], acc1[1][j], acc1[2][j], acc1[3][j]);
  }
  __syncthreads();
  if (tid < 200) {
    int k1 = tid / 10, k2 = (tid % 10) * 2;
    int mc = (k1 & 7) << 2, ms = ((20 + k1) & 7) << 2;
    int m0 = (k2 & 7) << 2, m1 = ((k2 + 1) & 7) << 2;
    const float* tgc = lds + k1 * 128;
    const float* tgs = lds + (20 + k1) * 128;
    const float* p0 = lds + 5120 + k2 * 256;
    const float* p1 = lds + 5120 + (k2 + 1) * 256;
    float Ac0 = 0.f, As0 = 0.f, Bc0 = 0.f, Bs0 = 0.f;
    float Ac1 = 0.f, As1 = 0.f, Bc1 = 0.f, Bs1 = 0.f;
    for (int t = 0; t < 128; t += 4) {
      float4 tc = *(const float4*)(tgc + (t ^ mc));
      float4 ts = *(const float4*)(tgs + (t ^ ms));
      float4 pc0 = *(const float4*)(p0 + (t ^ m0));
      float4 ps0 = *(const float4*)(p0 + 128 + (t ^ m0));
      float4 pc1 = *(const float4*)(p1 + (t ^ m1));
      float4 ps1 = *(const float4*)(p1 + 128 + (t ^ m1));
      Ac0 += tc.x*pc0.x + tc.y*pc0.y + tc.z*pc0.z + tc.w*pc0.w;
      As0 += ts.x*pc0.x + ts.y*pc0.y + ts.z*pc0.z + ts.w*pc0.w;
      Bc0 += tc.x*ps0.x + tc.y*ps0.y + tc.z*ps0.z + tc.w*ps0.w;
      Bs0 += ts.x*ps0.x + ts.y*ps0.y + ts.z*ps0.z + ts.w*ps0.w;
      Ac1 += tc.x*pc1.x + tc.y*pc1.y + tc.z*pc1.z + tc.w*pc1.w;
      As1 += ts.x*pc1.x + ts.y*pc1.y + ts.z*pc1.z + ts.w*pc1.w;
      Bc1 += tc.x*ps1.x + tc.y*ps1.y + tc.z*ps1.z + tc.w*ps1.w;
      Bs1 += ts.x*ps1.x + ts.y*ps1.y + ts.z*ps1.z + ts.w*ps1.w;
    }
    float sa, ca, sb, cb;
    sincosf(THETA * (float)(k1 + k2), &sa, &ca);
    sincosf(THETA * (float)(k1 + k2 + 1), &sb, &cb);
    int bc1 = bc0 + 1;
    X1[(k1 * 20 + k2) * 1024 + bc1] = (Ac0 - Bs0) * (1.f - sa) - (As0 + Bc0) * ca;
    X1[(k1 * 20 + k2 + 1) * 1024 + bc1] = (Ac1 - Bs1) * (1.f - sb) - (As1 + Bc1) * cb;
  }
}

// ---- k3: m-major. One block per m (400 blocks). O[(b*64+o)*400+m]
__global__ void k3_mix(const float* __restrict__ X1, const float* __restrict__ wbT,
                       float* __restrict__ O) {
  __shared__ float Xp[16][64], Xm[16][64];
  int m = blockIdx.x;
  int i = m / 20, j = m - i * 20;
  int nm = ((20 - i) % 20) * 20 + ((20 - j) % 20);
  int tid = threadIdx.x;
  const float sc = 0.5f / 16384.0f;
  float g[9]; gauss9(g);
  {
    int bl = tid >> 6, c = tid & 63;
#pragma unroll
    for (int it = 0; it < 4; ++it) {
      int b = bl * 4 + it;
      float sa = 0.f, sn = 0.f;
#pragma unroll
      for (int tp = 0; tp < 9; ++tp) {
        int bb = b - 4 + tp; bb = bb < 0 ? 0 : (bb > 15 ? 15 : bb);
        sa += g[tp] * X1[m * 1024 + bb * 64 + c];
        sn += g[tp] * X1[nm * 1024 + bb * 64 + c];
      }
      Xp[b][c] = (sa + sn) * sc; Xm[b][c] = (sa - sn) * sc;
    }
  }
  __syncthreads();
  int o = tid & 63, bq = tid >> 6;   // wave-uniform bq -> LDS broadcast reads
  float acc[4] = {0.f, 0.f, 0.f, 0.f};
#pragma unroll 4
  for (int c = 0; c < 64; ++c) {
    float wp = wbT[(c * 400 + m) * 64 + o];
    float wm = wbT[(c * 400 + nm) * 64 + o];
#pragma unroll
    for (int k = 0; k < 4; ++k)
      acc[k] += Xp[bq * 4 + k][c] * wp + Xm[bq * 4 + k][c] * wm;
  }
#pragma unroll
  for (int k = 0; k < 4; ++k)
    O[((bq * 4 + k) * 64 + o) * 400 + m] = acc[k];
}

// ---- k5b: per (b,o). Only v in [0,32] u [96,127] nonzero (RB2g mask).
__global__ void __launch_bounds__(256) k5b_final(const float* __restrict__ O,
                                                 const float* __restrict__ L2g,
                                                 const float* __restrict__ RB2g,
                                                 float* __restrict__ out) {
  __shared__ float Os[400];
  __shared__ float Rs[42 * 128];
  int bo = blockIdx.x, tid = threadIdx.x;
  for (int t = tid; t < 400; t += 256) Os[t] = O[bo * 400 + t];
  __syncthreads();
  const float4* Bc4 = (const float4*)RB2g;             // rows 0..20
  const float4* Bs4 = (const float4*)(RB2g + 21 * 128);
  {
    int rg = tid & 7;                 // row-group (rg<7: rows 6rg..6rg+5)
    int vqIdx = tid >> 3;             // 0..31; live for vqIdx<17
    int vq = (vqIdx < 9) ? vqIdx : vqIdx + 15;   // 0..8, 24..31
    if (rg < 7 && vqIdx < 17) {
      int r0 = rg * 6;
      float4 a[6];
#pragma unroll
      for (int q = 0; q < 6; ++q) a[q] = make_float4(0.f, 0.f, 0.f, 0.f);
      for (int k2 = 0; k2 <= 20; ++k2) {
        float4 bc4 = Bc4[k2 * 32 + vq];
        float4 bs4 = Bs4[k2 * 32 + vq];
#pragma unroll
        for (int q = 0; q < 6; ++q) {
          int r = r0 + q;
          bool isS = (r >= 21);
          int A = isS ? (r - 21) : r;
          if (k2 < 20 && A < 20) {
            float ov = Os[A * 20 + k2];
            const float4 b = isS ? bs4 : bc4;
            float s = isS ? -ov : ov;
            a[q].x += s * b.x; a[q].y += s * b.y; a[q].z += s * b.z; a[q].w += s * b.w;
          }
          if (k2 >= 1 && A >= 1) {
            float ov = Os[(A - 1) * 20 + (k2 - 1)];
            const float4 b = isS ? bc4 : bs4;
            a[q].x -= ov * b.x; a[q].y -= ov * b.y; a[q].z -= ov * b.z; a[q].w -= ov * b.w;
          }
        }
      }
#pragma unroll
      for (int q = 0; q < 6; ++q)
        *(float4*)&Rs[(r0 + q) * 128 + vq * 4] = a[q];
    }
  }
  __syncthreads();
  long base = (long)bo * 16384;
  // main GEMM: half 0 (waves 0-1): v 0..31; half 1 (waves 2-3): v 96..127
  {
    int half = tid >> 7;
    int uu = (tid >> 3) & 15;  int u0 = uu * 8;
    int vv = tid & 7;          int v0 = half ? (96 + vv * 4) : vv * 4;
    float acc[8][4];
#pragma unroll
    for (int a = 0; a < 8; ++a)
#pragma unroll
      for (int b = 0; b < 4; ++b) acc[a][b] = 0.f;
    for (int r = 0; r < 42; ++r) {
      float4 a0 = *(const float4*)(L2g + r * 128 + u0);
      float4 a1 = *(const float4*)(L2g + r * 128 + u0 + 4);
      float4 b0 = *(const float4*)&Rs[r * 128 + v0];
      float av[8] = {a0.x, a0.y, a0.z, a0.w, a1.x, a1.y, a1.z, a1.w};
      float bv[4] = {b0.x, b0.y, b0.z, b0.w};
#pragma unroll
      for (int a = 0; a < 8; ++a)
#pragma unroll
        for (int b = 0; b < 4; ++b) acc[a][b] += av[a] * bv[b];
    }
#pragma unroll
    for (int a = 0; a < 8; ++a)
      *(float4*)&out[base + (u0 + a) * 128 + v0] =
          make_float4(acc[a][0], acc[a][1], acc[a][2], acc[a][3]);
  }
  // v = 32 column (only nonzero col in vq group 8)
  if (tid < 128) {
    float d = 0.f;
    for (int r = 0; r < 42; ++r) d += L2g[r * 128 + tid] * Rs[r * 128 + 32];
    out[base + tid * 128 + 32] = d;
  }
  // zero-fill v 33..95: per u, scalars 33-35 + float4 at 36..92
  float4 z4 = make_float4(0.f, 0.f, 0.f, 0.f);
  for (int jj = tid; jj < 2048; jj += 256) {
    int u = jj >> 4, s = jj & 15;
    long p = base + (long)u * 128;
    if (s == 15) { out[p + 33] = 0.f; out[p + 34] = 0.f; out[p + 35] = 0.f; }
    else *(float4*)&out[p + 36 + 4 * s] = z4;
  }
}

extern "C" void kernel_launch(void* const* d_in, const int* in_sizes, int n_in,
                              void* d_out, int out_size, void* d_ws, size_t ws_size,
                              hipStream_t stream) {
  const float* x = (const float*)d_in[0];    // (16,64,128,128)
  const float* w1 = (const float*)d_in[1];   // (64,64,20,20)
  float* out = (float*)d_out;                // (16,64,128,128)
  float* ws = (float*)d_ws;

  float* X1 = ws;                  // 409,600
  float* O = X1 + 409600;          // 409,600
  float* wbT = O + 409600;         // 1,638,400
  float* L2g = wbT + 1638400;      // 5,376
  float* RB2g = L2g + 5376;        // 5,376   (total ~10 MB)

  hipLaunchKernelGGL(kBig, dim3(961), dim3(256), 0, stream,
                     x, w1, X1, wbT, L2g, RB2g);
  hipLaunchKernelGGL(k3_mix, dim3(400), dim3(256), 0, stream, X1, wbT, O);
  hipLaunchKernelGGL(k5b_final, dim3(1024), dim3(256), 0, stream, O, L2g, RB2g, out);
}

// Round 9
// 181.549 us; speedup vs baseline: 3.3379x; 1.0348x over previous
//
#include <hip/hip_runtime.h>

// SpectralConv2d DHT spectral conv, B=16, Cin=Cout=64, H=W=128, modes 20x20.
// All stages linear; blurs folded into bases/weights.
//   fwd:  X(k1,k2) = sum_n1 [cos(th k1 n1) Pc - sin(th k1 n1) Ps
//                            - sin(th k1(n1+1)) Pc1 - cos(th k1(n1+1)) Ps1]
//   rotation folded ALL the way (verified algebra):
//       X1 = (Ac-Bs)*(1-sin(th(k1+k2))) - (As+Bc)*cos(th(k1+k2))
//       Ac=sum c*Pc, As=sum s*Pc, Bc=sum c*Ps, Bs=sum s*Ps; c,s = cos/sin(th k1 n1)
//   inv (rank-42): y(u,v) = sum_{A=0..20} cosb(u,A)*RsC[A][v] + sinb(u,A)*RsS[A][v]
// 3 launches (cooperative grid.sync REJECTED: r6 = 519us, cross-XCD writeback;
// ~87us fixed harness overhead measured r6: 606 total w/ single 519us kernel):
//  kBig (961 blocks): blk0-511 k12 image-PAIRS (long pole first: loads start
//       earliest); blk512-959 w1 blur+T; blk960 L2g/RB2g bases.
//       k12 v7: register-prefetch pipeline — 4 static float4 tasks/thread
//       (16 VGPR, no conditionals; r4's failure was 7 conditional tasks),
//       chunk ch+1 loads issued before GEMM(ch) -> ~900cy HBM latency hidden
//       under ~1300cy of GEMM. Chunk-0 loads covered by Tgs sincos fill.
//  k3:  m-major (400 blocks): blur once for 16 b, weights reused x4 b.
//  k5b: masked-v: waves 0-1 v0..31, waves 2-3 v96..127; v=32 pass; zero-fill
//       (kept: harness may re-poison out between runs).

#define TWO_PI 6.283185307179586f
#define THETA (TWO_PI / 128.0f)

__device__ __forceinline__ void gauss9(float* g) {
  float s = 0.f;
#pragma unroll
  for (int t = 0; t < 9; ++t) { float d = (float)(t - 4); g[t] = expf(-0.5f * d * d); s += g[t]; }
  float inv = 1.f / s;
#pragma unroll
  for (int t = 0; t < 9; ++t) g[t] *= inv;
}

// ---- kBig: blk<512: k12 pairs; blk512-959: w1 blur; blk960: inverse bases
// k12 LDS (40960 B):
//   phase 1: [0..5120) Tgs[128][40]; [5120..7232) xs0[16][132]; [7232..9344) xs1
//   phase 2: [0..5120) TgT[40][128] row-XOR ((r&7)<<2);
//            [5120..10240) Pm2[20][256] XOR ((k2&7)<<2) — scatter+combine per img
__global__ void __launch_bounds__(256, 4) kBig(
    const float* __restrict__ x, const float* __restrict__ w1,
    float* __restrict__ X1, float* __restrict__ wbT,
    float* __restrict__ L2g, float* __restrict__ RB2g) {
  __shared__ float lds[10240];
  int tid = threadIdx.x;
  int blk = blockIdx.x;

  if (blk >= 512) {
    if (blk == 960) {
      // rank-42 inverse bases. rows 0..20 = cos(th u A), 21..41 = sin(th u A)
      for (int i = tid; i < 5376; i += 256) {
        int u = i / 42, t = i - u * 42;
        int A = (t < 21) ? t : t - 21;
        float a = (float)((u * A) & 127) * THETA;
        lds[u * 44 + t] = (t < 21) ? cosf(a) : sinf(a);
      }
      __syncthreads();
      float g[9]; gauss9(g);
      for (int i = tid; i < 5376; i += 256) {
        int u = i / 42, t = i - u * 42;
        float acc = 0.f;
#pragma unroll
        for (int tp = 0; tp < 9; ++tp) {
          int uc = u - 4 + tp; uc = uc < 0 ? 0 : (uc > 127 ? 127 : uc);
          acc += g[tp] * lds[uc * 44 + t];
        }
        L2g[t * 128 + u] = acc;
        bool keep = (u <= 32) || (u >= 96);
        RB2g[t * 128 + u] = keep ? acc : 0.f;
      }
      return;
    }
    // blur w1 over Cout + transpose: wbT[(c*400+m)*64+o]
    int bb = blk - 512;
    int c = bb / 7, chunk = bb % 7;
    int m0 = chunk * 64;
    int mw = 400 - m0; if (mw > 64) mw = 64;
    for (int t = tid; t < 4096; t += 256) {
      int o = t >> 6, mm = t & 63;
      lds[o * 69 + mm] = (mm < mw) ? w1[(c * 64 + o) * 400 + m0 + mm] : 0.f;
    }
    __syncthreads();
    float g[9]; gauss9(g);
    for (int t = tid; t < 4096; t += 256) {
      int mm = t >> 6, o = t & 63;
      if (mm >= mw) continue;
      float acc = 0.f;
#pragma unroll
      for (int tp = 0; tp < 9; ++tp) {
        int oc = o - 4 + tp; oc = oc < 0 ? 0 : (oc > 63 ? 63 : oc);
        acc += g[tp] * lds[oc * 69 + mm];
      }
      wbT[(c * 400 + m0 + mm) * 64 + o] = acc;
    }
    return;
  }

  // ---------------- k12: one block per image PAIR ----------------
  int bc0 = blk * 2;
  const float* xb0 = x + (long)bc0 * 16384;
  const float* xb1 = xb0 + 16384;

  // prefetch chunk 0 into registers (covered by Tgs fill below)
  float4 pv[4];
#pragma unroll
  for (int it = 0; it < 4; ++it) {
    int t = tid + it * 256;
    int n2l = t & 15, n1g = (t >> 4) & 31, im = t >> 9;
    const float* gp = (im ? xb1 : xb0) + n1g * 512 + n2l;
    pv[it] = make_float4(gp[0], gp[128], gp[256], gp[384]);
  }

  // Tgs[n2][col]: col<20 cos(th k2 n2), col>=20 sin. 10 sincos/thread, once.
  for (int i = tid; i < 2560; i += 256) {
    int n2 = i / 20, k2 = i - n2 * 20;
    float s, c;
    sincosf((float)((k2 * n2) & 127) * THETA, &s, &c);
    lds[n2 * 40 + k2] = c;
    lds[n2 * 40 + 20 + k2] = s;
  }

  int rg = tid & 31, cg = tid >> 5;   // 32 row-groups x 8 col-groups
  int r0 = rg * 4, c0 = cg * 5;
  float acc0[4][5], acc1[4][5];
#pragma unroll
  for (int i = 0; i < 4; ++i)
#pragma unroll
    for (int j = 0; j < 5; ++j) { acc0[i][j] = 0.f; acc1[i][j] = 0.f; }

  float* xs0 = lds + 5120;            // [16][132]
  float* xs1 = lds + 7232;            // [16][132]
  for (int ch = 0; ch < 8; ++ch) {
    __syncthreads();                  // xs free (and Tgs ready at ch==0)
    // write prefetched chunk to LDS (b128, conflict-free)
#pragma unroll
    for (int it = 0; it < 4; ++it) {
      int t = tid + it * 256;
      int n2l = t & 15, n1g = (t >> 4) & 31, im = t >> 9;
      float* dst = im ? xs1 : xs0;
      *(float4*)&dst[n2l * 132 + n1g * 4] = pv[it];
    }
    // issue next chunk's loads NOW — they fly during GEMM(ch)
    if (ch < 7) {
#pragma unroll
      for (int it = 0; it < 4; ++it) {
        int t = tid + it * 256;
        int n2l = t & 15, n1g = (t >> 4) & 31, im = t >> 9;
        const float* gp = (im ? xb1 : xb0) + n1g * 512 + (ch + 1) * 16 + n2l;
        pv[it] = make_float4(gp[0], gp[128], gp[256], gp[384]);
      }
    }
    __syncthreads();                  // xs ready
#pragma unroll 4
    for (int k = 0; k < 16; ++k) {
      float4 a0 = *(const float4*)&xs0[k * 132 + r0];     // conflict-free b128
      float4 a1 = *(const float4*)&xs1[k * 132 + r0];
      const float* tr = lds + (ch * 16 + k) * 40 + c0;    // broadcast b32 x5
      float bv[5] = {tr[0], tr[1], tr[2], tr[3], tr[4]};
      float a0v[4] = {a0.x, a0.y, a0.z, a0.w};
      float a1v[4] = {a1.x, a1.y, a1.z, a1.w};
#pragma unroll
      for (int i = 0; i < 4; ++i)
#pragma unroll
        for (int j = 0; j < 5; ++j) {
          acc0[i][j] += a0v[i] * bv[j];
          acc1[i][j] += a1v[i] * bv[j];
        }
    }
  }
  __syncthreads();
  // TgT build (overwrites Tgs): row r<20: cos(th r t); r>=20: sin(th (r-20) t)
  // stored at r*128 + (t ^ ((r&7)<<2)) -> conflict-free strided col reads
  for (int i = tid; i < 2560; i += 256) {
    int k1 = i >> 7, t = i & 127;
    float s, c;
    sincosf((float)((k1 * t) & 127) * THETA, &s, &c);
    lds[k1 * 128 + (t ^ ((k1 & 7) << 2))] = c;
    lds[(20 + k1) * 128 + (t ^ (((20 + k1) & 7) << 2))] = s;
  }
  // ---- image 0: scatter + combine ----
#pragma unroll
  for (int j = 0; j < 5; ++j) {
    int col = c0 + j;
    int k2 = (col < 20) ? col : col - 20;
    int part = (col < 20) ? 0 : 128;
    int m = (k2 & 7) << 2;
    *(float4*)&lds[5120 + k2 * 256 + ((part + r0) ^ m)] =
        make_float4(acc0[0][j], acc0[1][j], acc0[2][j], acc0[3][j]);
  }
  __syncthreads();
  if (tid < 200) {
    int k1 = tid / 10, k2 = (tid % 10) * 2;
    int mc = (k1 & 7) << 2, ms = ((20 + k1) & 7) << 2;
    int m0 = (k2 & 7) << 2, m1 = ((k2 + 1) & 7) << 2;
    const float* tgc = lds + k1 * 128;
    const float* tgs = lds + (20 + k1) * 128;
    const float* p0 = lds + 5120 + k2 * 256;
    const float* p1 = lds + 5120 + (k2 + 1) * 256;
    float Ac0 = 0.f, As0 = 0.f, Bc0 = 0.f, Bs0 = 0.f;
    float Ac1 = 0.f, As1 = 0.f, Bc1 = 0.f, Bs1 = 0.f;
    for (int t = 0; t < 128; t += 4) {
      float4 tc = *(const float4*)(tgc + (t ^ mc));
      float4 ts = *(const float4*)(tgs + (t ^ ms));
      float4 pc0 = *(const float4*)(p0 + (t ^ m0));
      float4 ps0 = *(const float4*)(p0 + 128 + (t ^ m0));
      float4 pc1 = *(const float4*)(p1 + (t ^ m1));
      float4 ps1 = *(const float4*)(p1 + 128 + (t ^ m1));
      Ac0 += tc.x*pc0.x + tc.y*pc0.y + tc.z*pc0.z + tc.w*pc0.w;
      As0 += ts.x*pc0.x + ts.y*pc0.y + ts.z*pc0.z + ts.w*pc0.w;
      Bc0 += tc.x*ps0.x + tc.y*ps0.y + tc.z*ps0.z + tc.w*ps0.w;
      Bs0 += ts.x*ps0.x + ts.y*ps0.y + ts.z*ps0.z + ts.w*ps0.w;
      Ac1 += tc.x*pc1.x + tc.y*pc1.y + tc.z*pc1.z + tc.w*pc1.w;
      As1 += ts.x*pc1.x + ts.y*pc1.y + ts.z*pc1.z + ts.w*pc1.w;
      Bc1 += tc.x*ps1.x + tc.y*ps1.y + tc.z*ps1.z + tc.w*ps1.w;
      Bs1 += ts.x*ps1.x + ts.y*ps1.y + ts.z*ps1.z + ts.w*ps1.w;
    }
    float sa, ca, sb, cb;
    sincosf(THETA * (float)(k1 + k2), &sa, &ca);
    sincosf(THETA * (float)(k1 + k2 + 1), &sb, &cb);
    X1[(k1 * 20 + k2) * 1024 + bc0] = (Ac0 - Bs0) * (1.f - sa) - (As0 + Bc0) * ca;
    X1[(k1 * 20 + k2 + 1) * 1024 + bc0] = (Ac1 - Bs1) * (1.f - sb) - (As1 + Bc1) * cb;
  }
  __syncthreads();   // combine img0 done reading Pm2
  // ---- image 1: scatter + combine ----
#pragma unroll
  for (int j = 0; j < 5; ++j) {
    int col = c0 + j;
    int k2 = (col < 20) ? col : col - 20;
    int part = (col < 20) ? 0 : 128;
    int m = (k2 & 7) << 2;
    *(float4*)&lds[5120 + k2 * 256 + ((part + r0) ^ m)] =
        make_float4(acc1[0][j], acc1[1][j], acc1[2][j], acc1[3][j]);
  }
  __syncthreads();
  if (tid < 200) {
    int k1 = tid / 10, k2 = (tid % 10) * 2;
    int mc = (k1 & 7) << 2, ms = ((20 + k1) & 7) << 2;
    int m0 = (k2 & 7) << 2, m1 = ((k2 + 1) & 7) << 2;
    const float* tgc = lds + k1 * 128;
    const float* tgs = lds + (20 + k1) * 128;
    const float* p0 = lds + 5120 + k2 * 256;
    const float* p1 = lds + 5120 + (k2 + 1) * 256;
    float Ac0 = 0.f, As0 = 0.f, Bc0 = 0.f, Bs0 = 0.f;
    float Ac1 = 0.f, As1 = 0.f, Bc1 = 0.f, Bs1 = 0.f;
    for (int t = 0; t < 128; t += 4) {
      float4 tc = *(const float4*)(tgc + (t ^ mc));
      float4 ts = *(const float4*)(tgs + (t ^ ms));
      float4 pc0 = *(const float4*)(p0 + (t ^ m0));
      float4 ps0 = *(const float4*)(p0 + 128 + (t ^ m0));
      float4 pc1 = *(const float4*)(p1 + (t ^ m1));
      float4 ps1 = *(const float4*)(p1 + 128 + (t ^ m1));
      Ac0 += tc.x*pc0.x + tc.y*pc0.y + tc.z*pc0.z + tc.w*pc0.w;
      As0 += ts.x*pc0.x + ts.y*pc0.y + ts.z*pc0.z + ts.w*pc0.w;
      Bc0 += tc.x*ps0.x + tc.y*ps0.y + tc.z*ps0.z + tc.w*ps0.w;
      Bs0 += ts.x*ps0.x + ts.y*ps0.y + ts.z*ps0.z + ts.w*ps0.w;
      Ac1 += tc.x*pc1.x + tc.y*pc1.y + tc.z*pc1.z + tc.w*pc1.w;
      As1 += ts.x*pc1.x + ts.y*pc1.y + ts.z*pc1.z + ts.w*pc1.w;
      Bc1 += tc.x*ps1.x + tc.y*ps1.y + tc.z*ps1.z + tc.w*ps1.w;
      Bs1 += ts.x*ps1.x + ts.y*ps1.y + ts.z*ps1.z + ts.w*ps1.w;
    }
    float sa, ca, sb, cb;
    sincosf(THETA * (float)(k1 + k2), &sa, &ca);
    sincosf(THETA * (float)(k1 + k2 + 1), &sb, &cb);
    int bc1 = bc0 + 1;
    X1[(k1 * 20 + k2) * 1024 + bc1] = (Ac0 - Bs0) * (1.f - sa) - (As0 + Bc0) * ca;
    X1[(k1 * 20 + k2 + 1) * 1024 + bc1] = (Ac1 - Bs1) * (1.f - sb) - (As1 + Bc1) * cb;
  }
}

// ---- k3: m-major. One block per m (400 blocks). O[(b*64+o)*400+m]
__global__ void k3_mix(const float* __restrict__ X1, const float* __restrict__ wbT,
                       float* __restrict__ O) {
  __shared__ float Xp[16][64], Xm[16][64];
  int m = blockIdx.x;
  int i = m / 20, j = m - i * 20;
  int nm = ((20 - i) % 20) * 20 + ((20 - j) % 20);
  int tid = threadIdx.x;
  const float sc = 0.5f / 16384.0f;
  float g[9]; gauss9(g);
  {
    int bl = tid >> 6, c = tid & 63;
#pragma unroll
    for (int it = 0; it < 4; ++it) {
      int b = bl * 4 + it;
      float sa = 0.f, sn = 0.f;
#pragma unroll
      for (int tp = 0; tp < 9; ++tp) {
        int bb = b - 4 + tp; bb = bb < 0 ? 0 : (bb > 15 ? 15 : bb);
        sa += g[tp] * X1[m * 1024 + bb * 64 + c];
        sn += g[tp] * X1[nm * 1024 + bb * 64 + c];
      }
      Xp[b][c] = (sa + sn) * sc; Xm[b][c] = (sa - sn) * sc;
    }
  }
  __syncthreads();
  int o = tid & 63, bq = tid >> 6;   // wave-uniform bq -> LDS broadcast reads
  float acc[4] = {0.f, 0.f, 0.f, 0.f};
#pragma unroll 4
  for (int c = 0; c < 64; ++c) {
    float wp = wbT[(c * 400 + m) * 64 + o];
    float wm = wbT[(c * 400 + nm) * 64 + o];
#pragma unroll
    for (int k = 0; k < 4; ++k)
      acc[k] += Xp[bq * 4 + k][c] * wp + Xm[bq * 4 + k][c] * wm;
  }
#pragma unroll
  for (int k = 0; k < 4; ++k)
    O[((bq * 4 + k) * 64 + o) * 400 + m] = acc[k];
}

// ---- k5b: per (b,o). Only v in [0,32] u [96,127] nonzero (RB2g mask).
__global__ void __launch_bounds__(256) k5b_final(const float* __restrict__ O,
                                                 const float* __restrict__ L2g,
                                                 const float* __restrict__ RB2g,
                                                 float* __restrict__ out) {
  __shared__ float Os[400];
  __shared__ float Rs[42 * 128];
  int bo = blockIdx.x, tid = threadIdx.x;
  for (int t = tid; t < 400; t += 256) Os[t] = O[bo * 400 + t];
  __syncthreads();
  const float4* Bc4 = (const float4*)RB2g;             // rows 0..20
  const float4* Bs4 = (const float4*)(RB2g + 21 * 128);
  {
    int rg = tid & 7;                 // row-group (rg<7: rows 6rg..6rg+5)
    int vqIdx = tid >> 3;             // 0..31; live for vqIdx<17
    int vq = (vqIdx < 9) ? vqIdx : vqIdx + 15;   // 0..8, 24..31
    if (rg < 7 && vqIdx < 17) {
      int r0 = rg * 6;
      float4 a[6];
#pragma unroll
      for (int q = 0; q < 6; ++q) a[q] = make_float4(0.f, 0.f, 0.f, 0.f);
      for (int k2 = 0; k2 <= 20; ++k2) {
        float4 bc4 = Bc4[k2 * 32 + vq];
        float4 bs4 = Bs4[k2 * 32 + vq];
#pragma unroll
        for (int q = 0; q < 6; ++q) {
          int r = r0 + q;
          bool isS = (r >= 21);
          int A = isS ? (r - 21) : r;
          if (k2 < 20 && A < 20) {
            float ov = Os[A * 20 + k2];
            const float4 b = isS ? bs4 : bc4;
            float s = isS ? -ov : ov;
            a[q].x += s * b.x; a[q].y += s * b.y; a[q].z += s * b.z; a[q].w += s * b.w;
          }
          if (k2 >= 1 && A >= 1) {
            float ov = Os[(A - 1) * 20 + (k2 - 1)];
            const float4 b = isS ? bc4 : bs4;
            a[q].x -= ov * b.x; a[q].y -= ov * b.y; a[q].z -= ov * b.z; a[q].w -= ov * b.w;
          }
        }
      }
#pragma unroll
      for (int q = 0; q < 6; ++q)
        *(float4*)&Rs[(r0 + q) * 128 + vq * 4] = a[q];
    }
  }
  __syncthreads();
  long base = (long)bo * 16384;
  // main GEMM: half 0 (waves 0-1): v 0..31; half 1 (waves 2-3): v 96..127
  {
    int half = tid >> 7;
    int uu = (tid >> 3) & 15;  int u0 = uu * 8;
    int vv = tid & 7;          int v0 = half ? (96 + vv * 4) : vv * 4;
    float acc[8][4];
#pragma unroll
    for (int a = 0; a < 8; ++a)
#pragma unroll
      for (int b = 0; b < 4; ++b) acc[a][b] = 0.f;
    for (int r = 0; r < 42; ++r) {
      float4 a0 = *(const float4*)(L2g + r * 128 + u0);
      float4 a1 = *(const float4*)(L2g + r * 128 + u0 + 4);
      float4 b0 = *(const float4*)&Rs[r * 128 + v0];
      float av[8] = {a0.x, a0.y, a0.z, a0.w, a1.x, a1.y, a1.z, a1.w};
      float bv[4] = {b0.x, b0.y, b0.z, b0.w};
#pragma unroll
      for (int a = 0; a < 8; ++a)
#pragma unroll
        for (int b = 0; b < 4; ++b) acc[a][b] += av[a] * bv[b];
    }
#pragma unroll
    for (int a = 0; a < 8; ++a)
      *(float4*)&out[base + (u0 + a) * 128 + v0] =
          make_float4(acc[a][0], acc[a][1], acc[a][2], acc[a][3]);
  }
  // v = 32 column (only nonzero col in vq group 8)
  if (tid < 128) {
    float d = 0.f;
    for (int r = 0; r < 42; ++r) d += L2g[r * 128 + tid] * Rs[r * 128 + 32];
    out[base + tid * 128 + 32] = d;
  }
  // zero-fill v 33..95: per u, scalars 33-35 + float4 at 36..92
  float4 z4 = make_float4(0.f, 0.f, 0.f, 0.f);
  for (int jj = tid; jj < 2048; jj += 256) {
    int u = jj >> 4, s = jj & 15;
    long p = base + (long)u * 128;
    if (s == 15) { out[p + 33] = 0.f; out[p + 34] = 0.f; out[p + 35] = 0.f; }
    else *(float4*)&out[p + 36 + 4 * s] = z4;
  }
}

extern "C" void kernel_launch(void* const* d_in, const int* in_sizes, int n_in,
                              void* d_out, int out_size, void* d_ws, size_t ws_size,
                              hipStream_t stream) {
  const float* x = (const float*)d_in[0];    // (16,64,128,128)
  const float* w1 = (const float*)d_in[1];   // (64,64,20,20)
  float* out = (float*)d_out;                // (16,64,128,128)
  float* ws = (float*)d_ws;

  float* X1 = ws;                  // 409,600
  float* O = X1 + 409600;          // 409,600
  float* wbT = O + 409600;         // 1,638,400
  float* L2g = wbT + 1638400;      // 5,376
  float* RB2g = L2g + 5376;        // 5,376   (total ~10 MB)

  hipLaunchKernelGGL(kBig, dim3(961), dim3(256), 0, stream,
                     x, w1, X1, wbT, L2g, RB2g);
  hipLaunchKernelGGL(k3_mix, dim3(400), dim3(256), 0, stream, X1, wbT, O);
  hipLaunchKernelGGL(k5b_final, dim3(1024), dim3(256), 0, stream, O, L2g, RB2g, out);
}